// Round 9
// baseline (51.138 us; speedup 1.0000x reference)
//
#include <hip/hip_runtime.h>
#include <stdint.h>

#define KDIM 2048
#define NEXP 64
#define MT   64              // tokens per block (16 per wave)
#define NCH  64              // k-chunks of 32
#define NTHR 256             // 4 waves, each: 16 tokens x 64 experts
#define DA   4               // A prefetch depth (chunks)
#define DB   2               // B prefetch depth (chunks)

typedef _Float16 half8 __attribute__((ext_vector_type(8)));
typedef __fp16  fp16x2 __attribute__((ext_vector_type(2)));
typedef float f32x4 __attribute__((ext_vector_type(4)));

__device__ __forceinline__ uint32_t pkrtz(float a, float b) {
    fp16x2 h = __builtin_amdgcn_cvt_pkrtz(a, b);
    return __builtin_bit_cast(uint32_t, h);
}

struct HL { half8 h; half8 l; };

// split 8 f32 into f16 hi (exact mantissa-truncate) + f16 lo (rtz residual)
__device__ __forceinline__ HL split8(float4 a, float4 b) {
    float y[8] = {a.x, a.y, a.z, a.w, b.x, b.y, b.z, b.w};
    uint32_t hw[4], lw[4];
    #pragma unroll
    for (int i = 0; i < 4; ++i) {
        float y0 = y[2 * i], y1 = y[2 * i + 1];
        float h0 = __builtin_bit_cast(float, __builtin_bit_cast(uint32_t, y0) & 0xFFFFE000u);
        float h1 = __builtin_bit_cast(float, __builtin_bit_cast(uint32_t, y1) & 0xFFFFE000u);
        hw[i] = pkrtz(h0, h1);
        lw[i] = pkrtz(y0 - h0, y1 - h1);
    }
    HL r;
    uint4 hv = {hw[0], hw[1], hw[2], hw[3]};
    uint4 lv = {lw[0], lw[1], lw[2], lw[3]};
    r.h = __builtin_bit_cast(half8, hv);
    r.l = __builtin_bit_cast(half8, lv);
    return r;
}

// W[64][2048] f32 -> fragment-ordered Wh/Wl:
// element index ((s*4+g)*64 + lane)*8 + j  maps to  W[g*16+(lane&15)][s*32+(lane>>4)*8+j]
__global__ __launch_bounds__(256) void prep_w(const float* __restrict__ W,
                                              _Float16* __restrict__ Wh,
                                              _Float16* __restrict__ Wl) {
    int t = blockIdx.x * 256 + threadIdx.x;   // 16384 threads = (s,g,l)
    int l = t & 63;
    int g = (t >> 6) & 3;
    int s = t >> 8;
    int e = g * 16 + (l & 15);
    int k = s * 32 + ((l >> 4) << 3);
    const float4* src = reinterpret_cast<const float4*>(W + (size_t)e * KDIM + k);
    HL r = split8(src[0], src[1]);
    *reinterpret_cast<half8*>(Wh + (size_t)t * 8) = r.h;
    *reinterpret_cast<half8*>(Wl + (size_t)t * 8) = r.l;
}

__global__ __launch_bounds__(NTHR, 1) void router_kernel(const float* __restrict__ x,
                                                         const _Float16* __restrict__ Wh,
                                                         const _Float16* __restrict__ Wl,
                                                         float* __restrict__ out_w,
                                                         float* __restrict__ out_i) {
    __shared__ float ss[MT][NEXP + 3];   // scores for top-2 only (17.2 KB)

    const int tid  = threadIdx.x;
    const int lane = tid & 63;
    const int wave = tid >> 6;           // wave owns tokens [wave*16, wave*16+16)
    const int tb   = blockIdx.x * MT;

    // A: per-lane fragment row pointer; x read EXACTLY once per block (R7 bug fixed)
    const float* xs = x + (size_t)(tb + wave * 16 + (lane & 15)) * KDIM + ((lane >> 4) << 3);
    // B: fragment-ordered; all 4 waves read the same stream (L1/L2-shared)
    const size_t bbase = (size_t)lane * 8;

    f32x4 acc[4];
    #pragma unroll
    for (int g = 0; g < 4; ++g) acc[g] = (f32x4){0.f, 0.f, 0.f, 0.f};

    float4 axr[DA][2];                   // [slot][seg]
    half8  bhr[DB][4], blr[DB][4];       // [slot][group]

    auto LOADA = [&](int slot, int c) {
        const float4* p = reinterpret_cast<const float4*>(xs + c * 32);
        axr[slot][0] = p[0];
        axr[slot][1] = p[1];
    };
    auto LOADB = [&](int slot, int c) {
        size_t base = (size_t)c * 4 * 64 * 8 + bbase;
        #pragma unroll
        for (int g = 0; g < 4; ++g) {
            bhr[slot][g] = *reinterpret_cast<const half8*>(Wh + base + g * 512);
            blr[slot][g] = *reinterpret_cast<const half8*>(Wl + base + g * 512);
        }
    };
    auto COMPUTE = [&](int sa, int sb) {
        HL a = split8(axr[sa][0], axr[sa][1]);
        #pragma unroll
        for (int g = 0; g < 4; ++g) {
            acc[g] = __builtin_amdgcn_mfma_f32_16x16x32_f16(a.h, bhr[sb][g], acc[g], 0, 0, 0);
            acc[g] = __builtin_amdgcn_mfma_f32_16x16x32_f16(a.l, bhr[sb][g], acc[g], 0, 0, 0);
            acc[g] = __builtin_amdgcn_mfma_f32_16x16x32_f16(a.h, blr[sb][g], acc[g], 0, 0, 0);
        }
    };

    // prologue: fill rings (A 4 chunks deep ~3000 cyc in flight; B 2 deep from L2)
    #pragma unroll
    for (int i = 0; i < DA; ++i) LOADA(i, i);
    #pragma unroll
    for (int i = 0; i < DB; ++i) LOADB(i, i);

    // main: chunks 0..59; all ring indices static after unroll (no scratch)
    for (int q = 0; q < 15; ++q) {
        #pragma unroll
        for (int i = 0; i < 4; ++i) {
            const int c = q * 4 + i;
            COMPUTE(i, i & 1);
            LOADA(i, c + DA);
            LOADB(i & 1, c + DB);
        }
    }
    // tail: chunks 60..63
    #pragma unroll
    for (int i = 0; i < 4; ++i) {
        const int c = 60 + i;
        COMPUTE(i, i & 1);
        if (c + DB < NCH) LOADB(i & 1, c + DB);   // static: true only for i<2
    }

    // ---- epilogue: top-2 per token ----
    #pragma unroll
    for (int g = 0; g < 4; ++g)
        #pragma unroll
        for (int r = 0; r < 4; ++r) {
            int tok = wave * 16 + (lane >> 4) * 4 + r;   // C/D: row=(lane>>4)*4+reg
            int e   = g * 16 + (lane & 15);              //      col=lane&15 (m89)
            ss[tok][e] = acc[g][r];
        }
    __syncthreads();

    if (tid < MT) {
        const int t = tid;
        float m1 = -1e30f, m2 = -1e30f;
        int i1 = 0, i2 = 0;
        // strict '>' keeps the lower index on ties, matching jax.lax.top_k
        #pragma unroll
        for (int e = 0; e < NEXP; ++e) {
            float v = ss[t][e];
            if (v > m1) { m2 = m1; i2 = i1; m1 = v; i1 = e; }
            else if (v > m2) { m2 = v; i2 = e; }
        }
        const int gt = tb + t;
        out_w[gt * 2 + 0] = m1;
        out_w[gt * 2 + 1] = m2;
        out_i[gt * 2 + 0] = (float)i1;
        out_i[gt * 2 + 1] = (float)i2;
    }
}

extern "C" void kernel_launch(void* const* d_in, const int* in_sizes, int n_in,
                              void* d_out, int out_size, void* d_ws, size_t ws_size,
                              hipStream_t stream) {
    const float* x = (const float*)d_in[0];   // [16384, 2048] f32
    const float* W = (const float*)d_in[1];   // [64, 2048]   f32
    float* out = (float*)d_out;               // [16384*2 weights][16384*2 indices]

    const int n_tokens = in_sizes[0] / KDIM;  // 16384
    _Float16* Whp = (_Float16*)d_ws;          // 256 KB, fragment-ordered
    _Float16* Wlp = Whp + (size_t)NEXP * KDIM;

    hipLaunchKernelGGL(prep_w, dim3((NEXP * KDIM / 8) / 256), dim3(256), 0, stream, W, Whp, Wlp);
    hipLaunchKernelGGL(router_kernel, dim3(n_tokens / MT), dim3(NTHR), 0, stream,
                       x, Whp, Wlp, out, out + 2 * (size_t)n_tokens);
}